// Round 10
// baseline (238.949 us; speedup 1.0000x reference)
//
#include <hip/hip_runtime.h>

// LIF membrane recurrence:
//   mem[t] = mem[t-1] * 0.25 * (1 - spike[t-1]) + x[t]
//   spike[t] = (mem[t] > 0.5) ? 1 : 0
// x: (T=8, 32,128,32,32) f32; out = spikes. Slab N = 4194304 f32.
//
// r2-r9 evidence: 3 source-level structures (upfront loads, keep-alive asm,
// named double-buffer pipeline) all land at 81-96us / 2.2-2.5 TB/s / VALU
// ~4% with VGPR 20/28/36 -> the compiler NEVER materializes >1 load in
// flight per wave; avg in-flight per wave ~0.3 wave-loads (Little's law).
// Hints are unenforceable. This round: the 8 timestep loads are VOLATILE
// INLINE-ASM global_load_dwordx4 -- volatile asm order is architecturally
// pinned, so all 8 loads issue before the single s_waitcnt vmcnt(0)
// (store queue empty at that point -> waits on loads only), then
// sched_barrier(0) fences the scheduler (rule #18), then compute + stores.

#define LIF_T 8
#define LIF_N (32 * 128 * 32 * 32)      // 4194304 f32
#define LIF_N4 (LIF_N / 4)              // 1048576 vec4 columns

typedef float f32x4 __attribute__((ext_vector_type(4)));

__global__ __launch_bounds__(256) void lif_kernel(
    const f32x4* __restrict__ x4, f32x4* __restrict__ o4) {
    const int i = blockIdx.x * 256 + threadIdx.x;   // vec4 column index
    const f32x4* __restrict__ p = x4 + i;

    // Phase 1: 8 loads, issue order pinned by volatile asm. 8 KB/wave in
    // flight -- MLP=8 by construction, not by scheduler goodwill.
    f32x4 v0, v1, v2, v3, v4, v5, v6, v7;
#define ALOAD(vr, t)                                                       \
    asm volatile("global_load_dwordx4 %0, %1, off"                         \
                 : "=v"(vr)                                                \
                 : "v"(p + (size_t)(t) * LIF_N4))
    ALOAD(v0, 0);
    ALOAD(v1, 1);
    ALOAD(v2, 2);
    ALOAD(v3, 3);
    ALOAD(v4, 4);
    ALOAD(v5, 5);
    ALOAD(v6, 6);
    ALOAD(v7, 7);
#undef ALOAD
    // All 8 retire here; no stores outstanding yet, so this waits on loads
    // only. sched_barrier stops the scheduler hoisting consumers above it.
    asm volatile("s_waitcnt vmcnt(0)" ::: "memory");
    __builtin_amdgcn_sched_barrier(0);

    float mx = 0.f, my = 0.f, mz = 0.f, mw = 0.f;   // membrane
    float sx = 0.f, sy = 0.f, sz = 0.f, sw = 0.f;   // spike (0/1)

    // mem*d is EXACT (d is 0 or 0.25, pow2); the single rounded add matches
    // numpy bit-for-bit, so (mem > 0.5) can never flip vs ref.
#define LIF_STEP(vt, t)                                                    \
    {                                                                      \
        const float dx = (sx != 0.f) ? 0.f : 0.25f;                        \
        const float dy = (sy != 0.f) ? 0.f : 0.25f;                        \
        const float dz = (sz != 0.f) ? 0.f : 0.25f;                        \
        const float dw = (sw != 0.f) ? 0.f : 0.25f;                        \
        mx = mx * dx + (vt).x;                                             \
        my = my * dy + (vt).y;                                             \
        mz = mz * dz + (vt).z;                                             \
        mw = mw * dw + (vt).w;                                             \
        sx = (mx > 0.5f) ? 1.f : 0.f;                                      \
        sy = (my > 0.5f) ? 1.f : 0.f;                                      \
        sz = (mz > 0.5f) ? 1.f : 0.f;                                      \
        sw = (mw > 0.5f) ? 1.f : 0.f;                                      \
        f32x4 s;                                                           \
        s.x = sx; s.y = sy; s.z = sz; s.w = sw;                            \
        o4[(size_t)(t) * LIF_N4 + i] = s;                                  \
    }

    LIF_STEP(v0, 0)
    LIF_STEP(v1, 1)
    LIF_STEP(v2, 2)
    LIF_STEP(v3, 3)
    LIF_STEP(v4, 4)
    LIF_STEP(v5, 5)
    LIF_STEP(v6, 6)
    LIF_STEP(v7, 7)
#undef LIF_STEP
}

extern "C" void kernel_launch(void* const* d_in, const int* in_sizes, int n_in,
                              void* d_out, int out_size, void* d_ws, size_t ws_size,
                              hipStream_t stream) {
    const f32x4* x4 = (const f32x4*)d_in[0];
    f32x4* o4 = (f32x4*)d_out;
    const int blocks = LIF_N4 / 256;    // 4096
    lif_kernel<<<blocks, 256, 0, stream>>>(x4, o4);
}